// Round 6
// baseline (831.883 us; speedup 1.0000x reference)
//
#include <hip/hip_runtime.h>
#include <hip/hip_bf16.h>
#include <stdint.h>

typedef __bf16 bf16;
typedef __bf16 bf16x8 __attribute__((ext_vector_type(8)));
typedef float floatx4 __attribute__((ext_vector_type(4)));

#define N_NODES 20000
#define MP 20096          // 157*128, padded M
#define HDIM 512
#define KP 1088           // 1029 padded to multiple of 64 (17 BK-iters, 136 chunks)
#define KCH 136
#define FEATD 1029
#define NUM_GAT 5
#define ROWT (MP / 128)   // 157 row tiles
#define ZBLK ((N_NODES + 255) / 256)   // extra agg blocks to zero next s/t buf

// ---- async global->LDS, 16B per lane; LDS base must be wave-uniform ----------
typedef __attribute__((address_space(1))) void as1_void;
typedef __attribute__((address_space(3))) void as3_void;
__device__ __forceinline__ void gl_lds16(const void* g, void* l) {
  __builtin_amdgcn_global_load_lds(
      (as1_void*)(uintptr_t)g, (as3_void*)(uintptr_t)l, 16, 0, 0);
}

// ------- pack x = concat(feat, goal, info) fp32 -> bf16 [MP][KP]; also zero cur
__global__ void pack_kernel(const float* __restrict__ a, const float* __restrict__ goal,
                            const float* __restrict__ info, bf16* __restrict__ xp,
                            int* __restrict__ cur) {
  int idx = blockIdx.x * 256 + threadIdx.x;
  if (idx <= N_NODES) cur[idx] = 0;          // fused zero_kernel
  if (idx >= MP * KCH) return;
  int row = idx / KCH, c = idx % KCH;
  bf16x8 o = {};
  if (row < N_NODES) {
    if (c < 64) {
      const float* p = a + (size_t)row * 512 + c * 8;
      #pragma unroll
      for (int j = 0; j < 8; ++j) o[j] = (bf16)p[j];
    } else if (c < 128) {
      const float* p = goal + (size_t)row * 512 + (c - 64) * 8;
      #pragma unroll
      for (int j = 0; j < 8; ++j) o[j] = (bf16)p[j];
    } else if (c == 128) {
      #pragma unroll
      for (int j = 0; j < 5; ++j) o[j] = (bf16)info[(size_t)row * 5 + j];
    }
  }
  *(bf16x8*)(xp + (size_t)row * KP + c * 8) = o;
}

// ------- LDS-tiled transpose: 8 square 512x512 fp32 -> bf16 [512][512] ---------
struct Ptr8 { const float* p[8]; };
__global__ __launch_bounds__(256) void transpose_sq_kernel(Ptr8 srcs, bf16* __restrict__ dst) {
  __shared__ float tile[64][65];
  int b = blockIdx.x;                  // 8 mats x 64 tiles
  int z = b >> 6, rem = b & 63;
  int kt = rem >> 3, nt = rem & 7;
  int k0 = kt * 64, n0 = nt * 64;
  const float* src = srcs.p[z];
  #pragma unroll
  for (int i = 0; i < 16; ++i) {
    int id = threadIdx.x + i * 256;
    int kk = id >> 6, nn = id & 63;
    tile[kk][nn] = src[(size_t)(k0 + kk) * 512 + n0 + nn];
  }
  __syncthreads();
  #pragma unroll
  for (int i = 0; i < 16; ++i) {
    int id = threadIdx.x + i * 256;
    int nn = id >> 6, kk = id & 63;
    dst[(size_t)z * 512 * 512 + (size_t)(n0 + nn) * 512 + k0 + kk] = (bf16)tile[kk][nn];
  }
}

// ------- LDS-tiled transpose: 2 wide 1029x512 fp32 -> bf16 [512][1088], pad ----
struct Ptr2 { const float* p[2]; };
__global__ __launch_bounds__(256) void transpose_wide_kernel(Ptr2 srcs, bf16* __restrict__ dst) {
  __shared__ float tile[64][65];
  int b = blockIdx.x;                  // 2 mats x (17 ktiles x 8 ntiles)
  int z = b / 136, rem = b % 136;
  int kt = rem >> 3, nt = rem & 7;
  int k0 = kt * 64, n0 = nt * 64;
  const float* src = srcs.p[z];
  #pragma unroll
  for (int i = 0; i < 16; ++i) {
    int id = threadIdx.x + i * 256;
    int kk = id >> 6, nn = id & 63;
    int k = k0 + kk;
    tile[kk][nn] = (k < FEATD) ? src[(size_t)k * 512 + n0 + nn] : 0.f;
  }
  __syncthreads();
  #pragma unroll
  for (int i = 0; i < 16; ++i) {
    int id = threadIdx.x + i * 256;
    int nn = id >> 6, kk = id & 63;
    dst[(size_t)z * 512 * KP + (size_t)(n0 + nn) * KP + k0 + kk] = (bf16)tile[kk][nn];
  }
}

// ---------------- CSR build ----------------------------------------------------
__global__ void hist_kernel(const int* __restrict__ src, int* __restrict__ cnt, int E) {
  int e = blockIdx.x * 256 + threadIdx.x;
  if (e < E) atomicAdd(&cnt[src[e]], 1);
}
__global__ __launch_bounds__(1024) void scan_kernel(int* __restrict__ cnt,
                                                    int* __restrict__ off, int n) {
  __shared__ int wsum[16];
  __shared__ int carry_s;
  int tid = threadIdx.x, lane = tid & 63, w = tid >> 6;
  if (tid == 0) carry_s = 0;
  __syncthreads();
  for (int base = 0; base < n; base += 1024) {
    int i = base + tid;
    int v = (i < n) ? cnt[i] : 0;
    int x = v;  // inclusive wave scan
    #pragma unroll
    for (int o = 1; o < 64; o <<= 1) {
      int y = __shfl_up(x, o);
      if (lane >= o) x += y;
    }
    if (lane == 63) wsum[w] = x;
    __syncthreads();
    int wpre = 0;
    for (int j = 0; j < w; ++j) wpre += wsum[j];
    int incl = x + wpre;
    int c = carry_s;
    if (i < n) { int ex = c + incl - v; off[i] = ex; cnt[i] = ex; }
    __syncthreads();
    if (tid == 1023) carry_s = c + incl;
    __syncthreads();
  }
  if (tid == 0) off[n] = carry_s;
}
__global__ void scatter_kernel(const int* __restrict__ src, const int* __restrict__ dstv,
                               int* __restrict__ cur, int* __restrict__ sdst, int E) {
  int e = blockIdx.x * 256 + threadIdx.x;
  if (e < E) {
    int p = atomicAdd(&cur[src[e]], 1);
    sdst[p] = dstv[e];
  }
}

// ------- bf16 MFMA GEMM v4: C[M][512] = A[M][K] @ BT[512][K]^T -----------------
// v7/v8 (128x64, A+B in LDS) was LDS-read-bound: per kk-phase per CU,
// ds_read demand 643 cyc vs MFMA 480. v4 fix: B is L2-resident (512KB,
// reused by all 157 row-blocks) -> load B fragments DIRECTLY from global
// into registers (16-line/wave gathers, full 64B line use), drop sB
// entirely. LDS traffic -33%, A-only dbuf = 32KB -> tile grows to 128x128
// with 64x64 per-wave acc (16 MFMA per 4 A-reads): per-CU MFMA 960+ cyc vs
// LDS 428 / L2-B ~857 -> MFMA-bound. Grid 628 blocks = single round.
// vmcnt safety with mixed B globals: vmcnt retires in ISSUE order and A-cur
// is always oldest -> vmcnt(4) (the 4 just-issued A-next gl_lds) can only
// over-wait, never under-wait.
__global__ __launch_bounds__(256, 3) void gemm_kernel(
    const bf16* __restrict__ A, const bf16* __restrict__ BT, bf16* __restrict__ C,
    int K, const float* __restrict__ bias, int relu,
    const float* __restrict__ avec, float* __restrict__ s_out,
    float* __restrict__ t_out, float* __restrict__ s_zero,
    float* __restrict__ t_zero) {
  __shared__ __align__(16) bf16 sA[2][128 * 64];
  const int flat = blockIdx.x;
  const int rowT = ((flat >> 5) << 3) | (flat & 7);
  const int colT = (flat >> 3) & 3;
  if (rowT >= ROWT) return;
  const int tid = threadIdx.x;
  const int lane = tid & 63, wid = tid >> 6;
  const int wr = (wid >> 1) * 64;      // wave row offset: 0 or 64
  const int wc = (wid & 1) * 64;       // wave col offset: 0 or 64
  const int rowBase = rowT * 128;
  const int colBase = colT * 128;
  const int lrow = lane & 15, lquad = lane >> 4;
  const int xk = lrow & 7;  // read-side XOR key

  floatx4 acc[4][4] = {};
  const int nk = K >> 6;

  // per-lane B base pointers (row colBase+wc+ni*16+lrow, k-slot lquad*8)
  const bf16* bp[4];
  #pragma unroll
  for (int ni = 0; ni < 4; ++ni)
    bp[ni] = BT + (size_t)(colBase + wc + ni * 16 + lrow) * K + lquad * 8;

  auto stage = [&](int buf, int k0) {
    #pragma unroll
    for (int i = 0; i < 4; ++i) {
      int idx = tid + i * 256;            // 0..1023: A tile 128 rows x 8 chunks
      int rr = idx >> 3, cc = idx & 7;
      int gch = cc ^ (rr & 7);            // swizzled global chunk
      gl_lds16(A + (size_t)(rowBase + rr) * K + k0 + gch * 8,
               &sA[buf][(size_t)(wid * 64 + i * 256) * 8]);
    }
  };

  stage(0, 0);
  for (int kt = 0; kt < nk; ++kt) {
    const int cur = kt & 1;
    if (kt + 1 < nk) {
      stage(cur ^ 1, (kt + 1) << 6);
      // vmcnt(4): wait for current buffer's 4 A-loads; prefetch stays in flight.
      __builtin_amdgcn_s_waitcnt(0xF74);
    } else {
      __builtin_amdgcn_s_waitcnt(0xF70);  // vmcnt(0)
    }
    __builtin_amdgcn_s_barrier();
    #pragma unroll
    for (int kk = 0; kk < 2; ++kk) {
      bf16x8 af[4], bfr[4];
      #pragma unroll
      for (int ni = 0; ni < 4; ++ni)      // B from global (L2-hot)
        bfr[ni] = *(const bf16x8*)(bp[ni] + kt * 64 + kk * 32);
      #pragma unroll
      for (int mi = 0; mi < 4; ++mi)
        af[mi] = *(const bf16x8*)&sA[cur][(wr + mi * 16 + lrow) * 64 +
                                         (((kk * 4 + lquad) ^ xk) * 8)];
      #pragma unroll
      for (int mi = 0; mi < 4; ++mi)
        #pragma unroll
        for (int ni = 0; ni < 4; ++ni)
          acc[mi][ni] = __builtin_amdgcn_mfma_f32_16x16x32_bf16(af[mi], bfr[ni], acc[mi][ni], 0, 0, 0);
    }
    // ds_reads complete (consumed by MFMA) before this barrier; next stage()
    // may then safely overwrite the buffer other waves just read.
    __builtin_amdgcn_s_barrier();
  }

  #pragma unroll
  for (int ni = 0; ni < 4; ++ni) {
    int col = colBase + wc + ni * 16 + lrow;
    float bv = bias ? bias[col] : 0.f;
    #pragma unroll
    for (int mi = 0; mi < 4; ++mi) {
      #pragma unroll
      for (int r = 0; r < 4; ++r) {
        int row = rowBase + wr + mi * 16 + lquad * 4 + r;
        float v = acc[mi][ni][r] + bv;
        if (relu) v = fmaxf(v, 0.f);
        C[(size_t)row * HDIM + col] = (bf16)v;
      }
    }
  }

  // ---- fused s,t epilogue (GAT layers; raw acc: no bias/relu on this path)
  if (s_out) {
    float a1c[4], a2c[4];
    #pragma unroll
    for (int ni = 0; ni < 4; ++ni) {
      int col = colBase + wc + ni * 16 + lrow;
      a1c[ni] = avec[col];
      a2c[ni] = avec[512 + col];
    }
    #pragma unroll
    for (int mi = 0; mi < 4; ++mi) {
      #pragma unroll
      for (int r = 0; r < 4; ++r) {
        float ps = acc[mi][0][r] * a1c[0] + acc[mi][1][r] * a1c[1] +
                   acc[mi][2][r] * a1c[2] + acc[mi][3][r] * a1c[3];
        float pt = acc[mi][0][r] * a2c[0] + acc[mi][1][r] * a2c[1] +
                   acc[mi][2][r] * a2c[2] + acc[mi][3][r] * a2c[3];
        #pragma unroll
        for (int o = 1; o < 16; o <<= 1) {
          ps += __shfl_xor(ps, o);
          pt += __shfl_xor(pt, o);
        }
        if (lrow == 0) {
          int row = rowBase + wr + mi * 16 + lquad * 4 + r;
          if (row < N_NODES) {
            atomicAdd(&s_out[row], ps);
            atomicAdd(&t_out[row], pt);
          }
        }
      }
    }
  }
  // ---- zero the first GAT layer's s/t buffers (from the W3 GEMM)
  if (s_zero && colT == 0 && tid < 128) {
    int row = rowBase + tid;
    if (row < N_NODES) { s_zero[row] = 0.f; t_zero[row] = 0.f; }
  }
}

// ------- GAT aggregation v8: v3 structure (proven floor) + swizzled combine ----
// agg is latency/concurrency-bound at its structural floor (~46us, FETCH
// ~144MB = each XCD streams each needed h-row ~once). Extra ZBLK blocks zero
// the NEXT layer's s/t buffers (safe: this layer reads the OTHER buffer pair).
__global__ __launch_bounds__(256) void agg_kernel(
    const float* __restrict__ s, const float* __restrict__ t,
    const bf16* __restrict__ hp, const int* __restrict__ off,
    const int* __restrict__ sdst, bf16* __restrict__ hout, int ostride,
    float* __restrict__ s_znext, float* __restrict__ t_znext) {
  const int node = blockIdx.x;
  if (node >= N_NODES) {                    // zeroing blocks
    if (s_znext) {
      int i = (node - N_NODES) * 256 + threadIdx.x;
      if (i < N_NODES) { s_znext[i] = 0.f; t_znext[i] = 0.f; }
    }
    return;
  }
  __shared__ __align__(16) float sacc[4][512];
  __shared__ float sden[4];
  const int wid = threadIdx.x >> 6, lane = threadIdx.x & 63;
  const int beg = off[node], end = off[node + 1];
  const int cnt = end - beg;
  const int q = (cnt + 3) >> 2;        // per-wave contiguous chunk
  int jb = beg + wid * q;
  int je = jb + q;
  if (jb > end) jb = end;
  if (je > end) je = end;
  const float si = s[node];
  const int lane8 = lane * 8;

  float acc[8] = {0.f, 0.f, 0.f, 0.f, 0.f, 0.f, 0.f, 0.f};
  float den = 0.f;
  int j = jb;
  for (; j + 4 <= je; j += 4) {
    int d0 = sdst[j], d1 = sdst[j + 1], d2 = sdst[j + 2], d3 = sdst[j + 3];
    float t0 = t[d0], t1 = t[d1], t2 = t[d2], t3 = t[d3];
    bf16x8 v0 = *(const bf16x8*)(hp + (size_t)d0 * 512 + lane8);
    bf16x8 v1 = *(const bf16x8*)(hp + (size_t)d1 * 512 + lane8);
    bf16x8 v2 = *(const bf16x8*)(hp + (size_t)d2 * 512 + lane8);
    bf16x8 v3 = *(const bf16x8*)(hp + (size_t)d3 * 512 + lane8);
    float s0 = si + t0, s1 = si + t1, s2 = si + t2, s3 = si + t3;
    float l0 = s0 > 0.f ? s0 : 0.2f * s0;
    float l1 = s1 > 0.f ? s1 : 0.2f * s1;
    float l2 = s2 > 0.f ? s2 : 0.2f * s2;
    float l3 = s3 > 0.f ? s3 : 0.2f * s3;
    float e0 = __expf(-l0), e1 = __expf(-l1), e2 = __expf(-l2), e3 = __expf(-l3);
    den += (e0 + e1) + (e2 + e3);
    #pragma unroll
    for (int qq = 0; qq < 8; ++qq)
      acc[qq] += e0 * (float)v0[qq] + e1 * (float)v1[qq] +
                 e2 * (float)v2[qq] + e3 * (float)v3[qq];
  }
  for (; j < je; ++j) {
    int d = sdst[j];
    float sc = si + t[d];
    float lr = sc > 0.f ? sc : 0.2f * sc;
    float e = __expf(-lr);
    den += e;
    bf16x8 v = *(const bf16x8*)(hp + (size_t)d * 512 + lane8);
    #pragma unroll
    for (int qq = 0; qq < 8; ++qq) acc[qq] += e * (float)v[qq];
  }

  if (lane == 0) sden[wid] = den;   // den identical across lanes
  // swizzled 16B-chunk store: chunk f = lane*2+h at p = f ^ (lane&7);
  // p&7 covers all 8 bank groups across any 8 consecutive lanes.
  #pragma unroll
  for (int h = 0; h < 2; ++h) {
    int p = (lane * 2 + h) ^ (lane & 7);
    floatx4 val = {acc[h * 4 + 0], acc[h * 4 + 1], acc[h * 4 + 2], acc[h * 4 + 3]};
    *(floatx4*)&sacc[wid][p * 4] = val;
  }
  __syncthreads();
  if (wid == 0) {
    float inv = 1.f / (sden[0] + sden[1] + sden[2] + sden[3] + 1e-10f);
    bf16x8 o;
    #pragma unroll
    for (int h = 0; h < 2; ++h) {
      int p = (lane * 2 + h) ^ (lane & 7);
      floatx4 sum = *(const floatx4*)&sacc[0][p * 4];
      #pragma unroll
      for (int w = 1; w < 4; ++w) {
        floatx4 v = *(const floatx4*)&sacc[w][p * 4];
        sum[0] += v[0]; sum[1] += v[1]; sum[2] += v[2]; sum[3] += v[3];
      }
      #pragma unroll
      for (int x = 0; x < 4; ++x)
        o[h * 4 + x] = (bf16)fmaxf(sum[x] * inv, 0.f);   // relu
    }
    *(bf16x8*)(hout + (size_t)node * ostride + lane8) = o;
  }
}

// -------- final: out = sigmoid(t2 @ V3 + vb3), V3/vb3 fp32, out fp32 -----------
__global__ void final_kernel(const bf16* __restrict__ t2, const float* __restrict__ V3,
                             const float* __restrict__ vb3, float* __restrict__ out) {
  int gid = blockIdx.x * 256 + threadIdx.x;
  int node = gid >> 6, lane = gid & 63;
  if (node >= N_NODES) return;
  bf16x8 hv = *(const bf16x8*)(t2 + (size_t)node * 512 + lane * 8);
  float p = 0.f;
  #pragma unroll
  for (int q = 0; q < 8; ++q) p += (float)hv[q] * V3[lane * 8 + q];
  #pragma unroll
  for (int o = 32; o > 0; o >>= 1) p += __shfl_xor(p, o);
  if (lane == 0) {
    float z = p + vb3[0];
    out[node] = 1.f / (1.f + __expf(-z));
  }
}

// ------------------------------------------------------------------------------
extern "C" void kernel_launch(void* const* d_in, const int* in_sizes, int n_in,
                              void* d_out, int out_size, void* d_ws, size_t ws_size,
                              hipStream_t stream) {
  const float* feat = (const float*)d_in[0];
  const float* goal = (const float*)d_in[1];
  const float* info = (const float*)d_in[2];
  const int* esrc   = (const int*)d_in[3];
  const int* edst   = (const int*)d_in[4];
  const float* W1  = (const float*)d_in[5];
  const float* b1  = (const float*)d_in[6];
  const float* W2  = (const float*)d_in[7];
  const float* b2  = (const float*)d_in[8];
  const float* W3  = (const float*)d_in[9];
  const float* b3  = (const float*)d_in[10];
  const float* V1  = (const float*)d_in[11];
  const float* vb1 = (const float*)d_in[12];
  const float* V2  = (const float*)d_in[13];
  const float* vb2 = (const float*)d_in[14];
  const float* V3  = (const float*)d_in[15];
  const float* vb3 = (const float*)d_in[16];
  const float* gatW = (const float*)d_in[17];
  const float* gatA = (const float*)d_in[18];
  float* out = (float*)d_out;
  const int E = in_sizes[3];
  const size_t SQ = 512 * 512;

  // ---- carve workspace
  char* w = (char*)d_ws;
  auto alloc = [&](size_t bytes) {
    char* p = w;
    w += (bytes + 255) & ~(size_t)255;
    return p;
  };
  bf16* xpad = (bf16*)alloc((size_t)MP * KP * 2);
  bf16* wkt  = (bf16*)alloc((size_t)2 * 512 * KP * 2);   // [0]=W1T, [1]=V1T
  bf16* wsq  = (bf16*)alloc((size_t)8 * SQ * 2);         // W2,W3,V2,gatW[0..4]
  bf16* hA   = (bf16*)alloc((size_t)MP * 512 * 2);
  bf16* hB   = (bf16*)alloc((size_t)MP * 512 * 2);
  bf16* hp   = (bf16*)alloc((size_t)MP * 512 * 2);
  float* svA = (float*)alloc((size_t)N_NODES * 4);
  float* tvA = (float*)alloc((size_t)N_NODES * 4);
  float* svB = (float*)alloc((size_t)N_NODES * 4);
  float* tvB = (float*)alloc((size_t)N_NODES * 4);
  int* off   = (int*)alloc((size_t)(N_NODES + 1) * 4);
  int* cur   = (int*)alloc((size_t)(N_NODES + 1) * 4);
  int* sdst  = (int*)alloc((size_t)E * 4);

  bf16* w1t = wkt;
  bf16* v1t = wkt + (size_t)512 * KP;
  bf16* w2t = wsq;
  bf16* w3t = wsq + SQ;
  bf16* v2t = wsq + 2 * SQ;
  bf16* gwt = wsq + 3 * SQ;

  const int eb = (E + 255) / 256;

  // ---- pack x (+ zero cur), transpose+convert weights (LDS-tiled)
  pack_kernel<<<(MP * KCH + 255) / 256, 256, 0, stream>>>(feat, goal, info, xpad, cur);
  Ptr2 wide; wide.p[0] = W1; wide.p[1] = V1;
  transpose_wide_kernel<<<2 * 136, 256, 0, stream>>>(wide, wkt);
  Ptr8 sq;
  sq.p[0] = W2; sq.p[1] = W3; sq.p[2] = V2;
  for (int i = 0; i < NUM_GAT; ++i) sq.p[3 + i] = gatW + (size_t)i * SQ;
  transpose_sq_kernel<<<8 * 64, 256, 0, stream>>>(sq, wsq);

  // ---- CSR build (sorted-by-src gather lists)
  hist_kernel<<<eb, 256, 0, stream>>>(esrc, cur, E);
  scan_kernel<<<1, 1024, 0, stream>>>(cur, off, N_NODES);
  scatter_kernel<<<eb, 256, 0, stream>>>(esrc, edst, cur, sdst, E);

  const int gg = 640;  // 160 row tiles x 4 col tiles, XCD-swizzled flat grid
  // ---- input MLP3 (W3 gemm zeroes layer-0 s/t buffers in its epilogue)
  gemm_kernel<<<gg, 256, 0, stream>>>(xpad, w1t, hA, KP, b1, 1,
                                      nullptr, nullptr, nullptr, nullptr, nullptr);
  gemm_kernel<<<gg, 256, 0, stream>>>(hA, w2t, hB, 512, b2, 1,
                                      nullptr, nullptr, nullptr, nullptr, nullptr);
  gemm_kernel<<<gg, 256, 0, stream>>>(hB, w3t, hA, 512, b3, 0,
                                      nullptr, nullptr, nullptr, svA, tvA);

  // ---- GAT layers: gemm computes h'=h@Wg AND s,t (fused epilogue);
  //      agg's extra blocks zero the NEXT layer's s/t buffers.
  bf16* ha = hA;
  bf16* hb = hB;
  for (int i = 0; i < NUM_GAT; ++i) {
    float* sb = (i & 1) ? svB : svA;
    float* tb = (i & 1) ? tvB : tvA;
    float* sn = (i & 1) ? svA : svB;
    float* tn = (i & 1) ? tvA : tvB;
    gemm_kernel<<<gg, 256, 0, stream>>>(ha, gwt + (size_t)i * SQ, hp, 512,
                                        (const float*)nullptr, 0,
                                        gatA + (size_t)i * 1024, sb, tb,
                                        nullptr, nullptr);
    float* szn = (i < NUM_GAT - 1) ? sn : nullptr;
    float* tzn = (i < NUM_GAT - 1) ? tn : nullptr;
    if (i == NUM_GAT - 1) {
      agg_kernel<<<N_NODES + ZBLK, 256, 0, stream>>>(sb, tb, hp, off, sdst,
                                                     xpad, KP, szn, tzn);
    } else {
      agg_kernel<<<N_NODES + ZBLK, 256, 0, stream>>>(sb, tb, hp, off, sdst,
                                                     hb, 512, szn, tzn);
      bf16* tmp = ha; ha = hb; hb = tmp;
    }
  }

  // ---- output MLP3 + sigmoid (xpad already holds [h, goal, info])
  gemm_kernel<<<gg, 256, 0, stream>>>(xpad, v1t, hB, KP, vb1, 1,
                                      nullptr, nullptr, nullptr, nullptr, nullptr);
  gemm_kernel<<<gg, 256, 0, stream>>>(hB, v2t, hp, 512, vb2, 1,
                                      nullptr, nullptr, nullptr, nullptr, nullptr);
  final_kernel<<<(N_NODES * 64 + 255) / 256, 256, 0, stream>>>(hp, V3, vb3, out);
}

// Round 10
// 713.719 us; speedup vs baseline: 1.1656x; 1.1656x over previous
//
#include <hip/hip_runtime.h>
#include <hip/hip_bf16.h>
#include <stdint.h>

typedef __bf16 bf16;
typedef __bf16 bf16x8 __attribute__((ext_vector_type(8)));
typedef float floatx4 __attribute__((ext_vector_type(4)));

#define N_NODES 20000
#define MP 20096          // 157*128, padded M
#define HDIM 512
#define KP 1088           // 1029 padded to multiple of 64 (34 BK32-iters, 136 chunks)
#define KCH 136
#define FEATD 1029
#define NUM_GAT 5
#define ROWT (MP / 128)   // 157 row tiles

// ---- async global->LDS, 16B per lane; LDS base must be wave-uniform ----------
typedef __attribute__((address_space(1))) void as1_void;
typedef __attribute__((address_space(3))) void as3_void;
__device__ __forceinline__ void gl_lds16(const void* g, void* l) {
  __builtin_amdgcn_global_load_lds(
      (as1_void*)(uintptr_t)g, (as3_void*)(uintptr_t)l, 16, 0, 0);
}

// ------- pack x = concat(feat, goal, info) fp32 -> bf16 [MP][KP]; zero cur -----
__global__ void pack_kernel(const float* __restrict__ a, const float* __restrict__ goal,
                            const float* __restrict__ info, bf16* __restrict__ xp,
                            int* __restrict__ cur) {
  int idx = blockIdx.x * 256 + threadIdx.x;
  if (idx <= N_NODES) cur[idx] = 0;          // fused zero_kernel (proven r5/r6)
  if (idx >= MP * KCH) return;
  int row = idx / KCH, c = idx % KCH;
  bf16x8 o = {};
  if (row < N_NODES) {
    if (c < 64) {
      const float* p = a + (size_t)row * 512 + c * 8;
      #pragma unroll
      for (int j = 0; j < 8; ++j) o[j] = (bf16)p[j];
    } else if (c < 128) {
      const float* p = goal + (size_t)row * 512 + (c - 64) * 8;
      #pragma unroll
      for (int j = 0; j < 8; ++j) o[j] = (bf16)p[j];
    } else if (c == 128) {
      #pragma unroll
      for (int j = 0; j < 5; ++j) o[j] = (bf16)info[(size_t)row * 5 + j];
    }
  }
  *(bf16x8*)(xp + (size_t)row * KP + c * 8) = o;
}

// ------- LDS-tiled transpose: 8 square 512x512 fp32 -> bf16 [512][512] ---------
struct Ptr8 { const float* p[8]; };
__global__ __launch_bounds__(256) void transpose_sq_kernel(Ptr8 srcs, bf16* __restrict__ dst) {
  __shared__ float tile[64][65];
  int b = blockIdx.x;                  // 8 mats x 64 tiles
  int z = b >> 6, rem = b & 63;
  int kt = rem >> 3, nt = rem & 7;
  int k0 = kt * 64, n0 = nt * 64;
  const float* src = srcs.p[z];
  #pragma unroll
  for (int i = 0; i < 16; ++i) {
    int id = threadIdx.x + i * 256;
    int kk = id >> 6, nn = id & 63;
    tile[kk][nn] = src[(size_t)(k0 + kk) * 512 + n0 + nn];
  }
  __syncthreads();
  #pragma unroll
  for (int i = 0; i < 16; ++i) {
    int id = threadIdx.x + i * 256;
    int nn = id >> 6, kk = id & 63;
    dst[(size_t)z * 512 * 512 + (size_t)(n0 + nn) * 512 + k0 + kk] = (bf16)tile[kk][nn];
  }
}

// ------- LDS-tiled transpose: 2 wide 1029x512 fp32 -> bf16 [512][1088], pad ----
struct Ptr2 { const float* p[2]; };
__global__ __launch_bounds__(256) void transpose_wide_kernel(Ptr2 srcs, bf16* __restrict__ dst) {
  __shared__ float tile[64][65];
  int b = blockIdx.x;                  // 2 mats x (17 ktiles x 8 ntiles)
  int z = b / 136, rem = b % 136;
  int kt = rem >> 3, nt = rem & 7;
  int k0 = kt * 64, n0 = nt * 64;
  const float* src = srcs.p[z];
  #pragma unroll
  for (int i = 0; i < 16; ++i) {
    int id = threadIdx.x + i * 256;
    int kk = id >> 6, nn = id & 63;
    int k = k0 + kk;
    tile[kk][nn] = (k < FEATD) ? src[(size_t)k * 512 + n0 + nn] : 0.f;
  }
  __syncthreads();
  #pragma unroll
  for (int i = 0; i < 16; ++i) {
    int id = threadIdx.x + i * 256;
    int nn = id >> 6, kk = id & 63;
    dst[(size_t)z * 512 * KP + (size_t)(n0 + nn) * KP + k0 + kk] = (bf16)tile[kk][nn];
  }
}

// ---------------- CSR build ----------------------------------------------------
__global__ void hist_kernel(const int* __restrict__ src, int* __restrict__ cnt, int E) {
  int e = blockIdx.x * 256 + threadIdx.x;
  if (e < E) atomicAdd(&cnt[src[e]], 1);
}
__global__ __launch_bounds__(1024) void scan_kernel(int* __restrict__ cnt,
                                                    int* __restrict__ off, int n) {
  __shared__ int wsum[16];
  __shared__ int carry_s;
  int tid = threadIdx.x, lane = tid & 63, w = tid >> 6;
  if (tid == 0) carry_s = 0;
  __syncthreads();
  for (int base = 0; base < n; base += 1024) {
    int i = base + tid;
    int v = (i < n) ? cnt[i] : 0;
    int x = v;  // inclusive wave scan
    #pragma unroll
    for (int o = 1; o < 64; o <<= 1) {
      int y = __shfl_up(x, o);
      if (lane >= o) x += y;
    }
    if (lane == 63) wsum[w] = x;
    __syncthreads();
    int wpre = 0;
    for (int j = 0; j < w; ++j) wpre += wsum[j];
    int incl = x + wpre;
    int c = carry_s;
    if (i < n) { int ex = c + incl - v; off[i] = ex; cnt[i] = ex; }
    __syncthreads();
    if (tid == 1023) carry_s = c + incl;
    __syncthreads();
  }
  if (tid == 0) off[n] = carry_s;
}
__global__ void scatter_kernel(const int* __restrict__ src, const int* __restrict__ dstv,
                               int* __restrict__ cur, int* __restrict__ sdst, int E) {
  int e = blockIdx.x * 256 + threadIdx.x;
  if (e < E) {
    int p = atomicAdd(&cur[src[e]], 1);
    sdst[p] = dstv[e];
  }
}

// ------- bf16 MFMA GEMM v5: C[M][512] = A[M][K] @ BT[512][K]^T -----------------
// 128x128 tile, BK=32: LDS 2x(8+8)KB = 32KB -> 4 blocks/CU (16 waves), grid
// 640 ~ single round, AND per-wave op ratio 8 ds_read : 16 MFMA (2.0, vs
// v7's 1.33) -> per-CU LDS ~750cyc < MFMA ~920cyc: MFMA-bound for the first
// time. v7 (128x64 BK=64) was LDS-read-bound (~1125 vs 920). Swizzle
// re-derived for 64B row stride: store chunk cc^((rr>>1)&3), read chunk
// lquad^((lrow>>1)&3) -> per wave all 8 bank-quads covered 8x (structural
// minimum, no excess serialization). Counted vmcnt(4) keeps the next tile's
// 4 loads in flight across the barrier. Round-6 lesson kept: MFMA operands
// only from LDS.
__global__ __launch_bounds__(256, 4) void gemm_kernel(
    const bf16* __restrict__ A, const bf16* __restrict__ BT, bf16* __restrict__ C,
    int K, const float* __restrict__ bias, int relu) {
  __shared__ __align__(16) bf16 sA[2][128 * 32];
  __shared__ __align__(16) bf16 sB[2][128 * 32];
  const int flat = blockIdx.x;
  const int rowT = ((flat >> 5) << 3) | (flat & 7);
  const int colT = (flat >> 3) & 3;
  if (rowT >= ROWT) return;
  const int tid = threadIdx.x;
  const int lane = tid & 63, wid = tid >> 6;
  const int wr = (wid >> 1) * 64;      // wave row offset: 0 or 64
  const int wc = (wid & 1) * 64;       // wave col offset: 0 or 64
  const int rowBase = rowT * 128;
  const int colBase = colT * 128;
  const int lrow = lane & 15, lquad = lane >> 4;
  const int rchunk = lquad ^ ((lrow >> 1) & 3);   // read-side swizzled k-octet

  floatx4 acc[4][4] = {};
  const int nk = K >> 5;

  auto stage = [&](int buf, int k0) {
    #pragma unroll
    for (int i = 0; i < 2; ++i) {
      int idx = tid + i * 256;            // 0..511: A tile 128 rows x 4 chunks
      int rr = idx >> 2, cc = idx & 3;
      int gch = cc ^ ((rr >> 1) & 3);     // swizzled global chunk
      gl_lds16(A + (size_t)(rowBase + rr) * K + k0 + gch * 8,
               &sA[buf][(size_t)(wid * 64 + i * 256) * 8]);
    }
    #pragma unroll
    for (int i = 0; i < 2; ++i) {
      int idx = tid + i * 256;            // 0..511: B tile 128 rows x 4 chunks
      int rr = idx >> 2, cc = idx & 3;
      int gch = cc ^ ((rr >> 1) & 3);
      gl_lds16(BT + (size_t)(colBase + rr) * K + k0 + gch * 8,
               &sB[buf][(size_t)(wid * 64 + i * 256) * 8]);
    }
  };

  stage(0, 0);
  for (int kt = 0; kt < nk; ++kt) {
    const int cur = kt & 1;
    if (kt + 1 < nk) {
      stage(cur ^ 1, (kt + 1) << 5);
      // vmcnt(4): wait for current buffer's 4 loads; prefetch stays in flight.
      __builtin_amdgcn_s_waitcnt(0xF74);
    } else {
      __builtin_amdgcn_s_waitcnt(0xF70);  // vmcnt(0)
    }
    __builtin_amdgcn_s_barrier();
    {
      bf16x8 af[4], bfr[4];
      #pragma unroll
      for (int mi = 0; mi < 4; ++mi)
        af[mi] = *(const bf16x8*)&sA[cur][(wr + mi * 16 + lrow) * 32 + rchunk * 8];
      #pragma unroll
      for (int ni = 0; ni < 4; ++ni)
        bfr[ni] = *(const bf16x8*)&sB[cur][(wc + ni * 16 + lrow) * 32 + rchunk * 8];
      #pragma unroll
      for (int mi = 0; mi < 4; ++mi)
        #pragma unroll
        for (int ni = 0; ni < 4; ++ni)
          acc[mi][ni] = __builtin_amdgcn_mfma_f32_16x16x32_bf16(af[mi], bfr[ni], acc[mi][ni], 0, 0, 0);
    }
    // ds_reads complete (consumed by MFMA) before this barrier; next stage()
    // may then safely overwrite the buffer other waves just read.
    __builtin_amdgcn_s_barrier();
  }

  #pragma unroll
  for (int ni = 0; ni < 4; ++ni) {
    int col = colBase + wc + ni * 16 + lrow;
    float bv = bias ? bias[col] : 0.f;
    #pragma unroll
    for (int mi = 0; mi < 4; ++mi) {
      #pragma unroll
      for (int r = 0; r < 4; ++r) {
        int row = rowBase + wr + mi * 16 + lquad * 4 + r;
        float v = acc[mi][ni][r] + bv;
        if (relu) v = fmaxf(v, 0.f);
        C[(size_t)row * HDIM + col] = (bf16)v;
      }
    }
  }
}

// ---------------- s = h'@a1, t = h'@a2 (wave per node; a fp32) -----------------
__global__ void st_kernel(const bf16* __restrict__ hp, const float* __restrict__ a1,
                          const float* __restrict__ a2, float* __restrict__ s,
                          float* __restrict__ t) {
  int gid = blockIdx.x * 256 + threadIdx.x;
  int node = gid >> 6, lane = gid & 63;
  if (node >= N_NODES) return;
  bf16x8 hv = *(const bf16x8*)(hp + (size_t)node * 512 + lane * 8);
  float ps = 0.f, pt = 0.f;
  #pragma unroll
  for (int q = 0; q < 8; ++q) {
    float h = (float)hv[q];
    ps += h * a1[lane * 8 + q];
    pt += h * a2[lane * 8 + q];
  }
  #pragma unroll
  for (int o = 32; o > 0; o >>= 1) {
    ps += __shfl_xor(ps, o);
    pt += __shfl_xor(pt, o);
  }
  if (lane == 0) { s[node] = ps; t[node] = pt; }
}

// ------- GAT aggregation (v7, proven floor): 4 waves/node + swizzled combine ---
// agg is latency/concurrency-bound at its structural floor (~46us across 4
// structural variants; FETCH ~144MB = each XCD streams each needed h-row
// ~once for a random graph). den is lane-uniform: no cross-lane reduce.
__global__ __launch_bounds__(256) void agg_kernel(
    const float* __restrict__ s, const float* __restrict__ t,
    const bf16* __restrict__ hp, const int* __restrict__ off,
    const int* __restrict__ sdst, bf16* __restrict__ hout, int ostride) {
  __shared__ __align__(16) float sacc[4][512];
  __shared__ float sden[4];
  const int wid = threadIdx.x >> 6, lane = threadIdx.x & 63;
  const int node = blockIdx.x;
  const int beg = off[node], end = off[node + 1];
  const int cnt = end - beg;
  const int q = (cnt + 3) >> 2;        // per-wave contiguous chunk
  int jb = beg + wid * q;
  int je = jb + q;
  if (jb > end) jb = end;
  if (je > end) je = end;
  const float si = s[node];
  const int lane8 = lane * 8;

  float acc[8] = {0.f, 0.f, 0.f, 0.f, 0.f, 0.f, 0.f, 0.f};
  float den = 0.f;
  int j = jb;
  for (; j + 4 <= je; j += 4) {
    int d0 = sdst[j], d1 = sdst[j + 1], d2 = sdst[j + 2], d3 = sdst[j + 3];
    float t0 = t[d0], t1 = t[d1], t2 = t[d2], t3 = t[d3];
    bf16x8 v0 = *(const bf16x8*)(hp + (size_t)d0 * 512 + lane8);
    bf16x8 v1 = *(const bf16x8*)(hp + (size_t)d1 * 512 + lane8);
    bf16x8 v2 = *(const bf16x8*)(hp + (size_t)d2 * 512 + lane8);
    bf16x8 v3 = *(const bf16x8*)(hp + (size_t)d3 * 512 + lane8);
    float s0 = si + t0, s1 = si + t1, s2 = si + t2, s3 = si + t3;
    float l0 = s0 > 0.f ? s0 : 0.2f * s0;
    float l1 = s1 > 0.f ? s1 : 0.2f * s1;
    float l2 = s2 > 0.f ? s2 : 0.2f * s2;
    float l3 = s3 > 0.f ? s3 : 0.2f * s3;
    float e0 = __expf(-l0), e1 = __expf(-l1), e2 = __expf(-l2), e3 = __expf(-l3);
    den += (e0 + e1) + (e2 + e3);
    #pragma unroll
    for (int qq = 0; qq < 8; ++qq)
      acc[qq] += e0 * (float)v0[qq] + e1 * (float)v1[qq] +
                 e2 * (float)v2[qq] + e3 * (float)v3[qq];
  }
  for (; j < je; ++j) {
    int d = sdst[j];
    float sc = si + t[d];
    float lr = sc > 0.f ? sc : 0.2f * sc;
    float e = __expf(-lr);
    den += e;
    bf16x8 v = *(const bf16x8*)(hp + (size_t)d * 512 + lane8);
    #pragma unroll
    for (int qq = 0; qq < 8; ++qq) acc[qq] += e * (float)v[qq];
  }

  if (lane == 0) sden[wid] = den;   // den identical across lanes
  // swizzled 16B-chunk store: chunk f = lane*2+h at p = f ^ (lane&7);
  // p&7 covers all 8 bank groups across any 8 consecutive lanes.
  #pragma unroll
  for (int h = 0; h < 2; ++h) {
    int p = (lane * 2 + h) ^ (lane & 7);
    floatx4 val = {acc[h * 4 + 0], acc[h * 4 + 1], acc[h * 4 + 2], acc[h * 4 + 3]};
    *(floatx4*)&sacc[wid][p * 4] = val;
  }
  __syncthreads();
  if (wid == 0) {
    float inv = 1.f / (sden[0] + sden[1] + sden[2] + sden[3] + 1e-10f);
    bf16x8 o;
    #pragma unroll
    for (int h = 0; h < 2; ++h) {
      int p = (lane * 2 + h) ^ (lane & 7);
      floatx4 sum = *(const floatx4*)&sacc[0][p * 4];
      #pragma unroll
      for (int w = 1; w < 4; ++w) {
        floatx4 v = *(const floatx4*)&sacc[w][p * 4];
        sum[0] += v[0]; sum[1] += v[1]; sum[2] += v[2]; sum[3] += v[3];
      }
      #pragma unroll
      for (int x = 0; x < 4; ++x)
        o[h * 4 + x] = (bf16)fmaxf(sum[x] * inv, 0.f);   // relu
    }
    *(bf16x8*)(hout + (size_t)node * ostride + lane8) = o;
  }
}

// -------- final: out = sigmoid(t2 @ V3 + vb3), V3/vb3 fp32, out fp32 -----------
__global__ void final_kernel(const bf16* __restrict__ t2, const float* __restrict__ V3,
                             const float* __restrict__ vb3, float* __restrict__ out) {
  int gid = blockIdx.x * 256 + threadIdx.x;
  int node = gid >> 6, lane = gid & 63;
  if (node >= N_NODES) return;
  bf16x8 hv = *(const bf16x8*)(t2 + (size_t)node * 512 + lane * 8);
  float p = 0.f;
  #pragma unroll
  for (int q = 0; q < 8; ++q) p += (float)hv[q] * V3[lane * 8 + q];
  #pragma unroll
  for (int o = 32; o > 0; o >>= 1) p += __shfl_xor(p, o);
  if (lane == 0) {
    float z = p + vb3[0];
    out[node] = 1.f / (1.f + __expf(-z));
  }
}

// ------------------------------------------------------------------------------
extern "C" void kernel_launch(void* const* d_in, const int* in_sizes, int n_in,
                              void* d_out, int out_size, void* d_ws, size_t ws_size,
                              hipStream_t stream) {
  const float* feat = (const float*)d_in[0];
  const float* goal = (const float*)d_in[1];
  const float* info = (const float*)d_in[2];
  const int* esrc   = (const int*)d_in[3];
  const int* edst   = (const int*)d_in[4];
  const float* W1  = (const float*)d_in[5];
  const float* b1  = (const float*)d_in[6];
  const float* W2  = (const float*)d_in[7];
  const float* b2  = (const float*)d_in[8];
  const float* W3  = (const float*)d_in[9];
  const float* b3  = (const float*)d_in[10];
  const float* V1  = (const float*)d_in[11];
  const float* vb1 = (const float*)d_in[12];
  const float* V2  = (const float*)d_in[13];
  const float* vb2 = (const float*)d_in[14];
  const float* V3  = (const float*)d_in[15];
  const float* vb3 = (const float*)d_in[16];
  const float* gatW = (const float*)d_in[17];
  const float* gatA = (const float*)d_in[18];
  float* out = (float*)d_out;
  const int E = in_sizes[3];
  const size_t SQ = 512 * 512;

  // ---- carve workspace
  char* w = (char*)d_ws;
  auto alloc = [&](size_t bytes) {
    char* p = w;
    w += (bytes + 255) & ~(size_t)255;
    return p;
  };
  bf16* xpad = (bf16*)alloc((size_t)MP * KP * 2);
  bf16* wkt  = (bf16*)alloc((size_t)2 * 512 * KP * 2);   // [0]=W1T, [1]=V1T
  bf16* wsq  = (bf16*)alloc((size_t)8 * SQ * 2);         // W2,W3,V2,gatW[0..4]
  bf16* hA   = (bf16*)alloc((size_t)MP * 512 * 2);
  bf16* hB   = (bf16*)alloc((size_t)MP * 512 * 2);
  bf16* hp   = (bf16*)alloc((size_t)MP * 512 * 2);
  float* sv  = (float*)alloc((size_t)N_NODES * 4);
  float* tv  = (float*)alloc((size_t)N_NODES * 4);
  int* off   = (int*)alloc((size_t)(N_NODES + 1) * 4);
  int* cur   = (int*)alloc((size_t)(N_NODES + 1) * 4);
  int* sdst  = (int*)alloc((size_t)E * 4);

  bf16* w1t = wkt;
  bf16* v1t = wkt + (size_t)512 * KP;
  bf16* w2t = wsq;
  bf16* w3t = wsq + SQ;
  bf16* v2t = wsq + 2 * SQ;
  bf16* gwt = wsq + 3 * SQ;

  const int eb = (E + 255) / 256;

  // ---- pack x (+ zero cur), transpose+convert weights (LDS-tiled)
  pack_kernel<<<(MP * KCH + 255) / 256, 256, 0, stream>>>(feat, goal, info, xpad, cur);
  Ptr2 wide; wide.p[0] = W1; wide.p[1] = V1;
  transpose_wide_kernel<<<2 * 136, 256, 0, stream>>>(wide, wkt);
  Ptr8 sq;
  sq.p[0] = W2; sq.p[1] = W3; sq.p[2] = V2;
  for (int i = 0; i < NUM_GAT; ++i) sq.p[3 + i] = gatW + (size_t)i * SQ;
  transpose_sq_kernel<<<8 * 64, 256, 0, stream>>>(sq, wsq);

  // ---- CSR build (sorted-by-src gather lists)
  hist_kernel<<<eb, 256, 0, stream>>>(esrc, cur, E);
  scan_kernel<<<1, 1024, 0, stream>>>(cur, off, N_NODES);
  scatter_kernel<<<eb, 256, 0, stream>>>(esrc, edst, cur, sdst, E);

  const int gg = 640;  // 160 row tiles x 4 col tiles, XCD-swizzled flat grid
  // ---- input MLP3
  gemm_kernel<<<gg, 256, 0, stream>>>(xpad, w1t, hA, KP, b1, 1);
  gemm_kernel<<<gg, 256, 0, stream>>>(hA, w2t, hB, 512, b2, 1);
  gemm_kernel<<<gg, 256, 0, stream>>>(hB, w3t, hA, 512, b3, 0);

  // ---- GAT layers (layer 4 writes straight into xpad cols 0..511)
  bf16* ha = hA;
  bf16* hb = hB;
  for (int i = 0; i < NUM_GAT; ++i) {
    gemm_kernel<<<gg, 256, 0, stream>>>(ha, gwt + (size_t)i * SQ, hp, 512,
                                        (const float*)nullptr, 0);
    st_kernel<<<(N_NODES * 64 + 255) / 256, 256, 0, stream>>>(
        hp, gatA + (size_t)i * 1024, gatA + (size_t)i * 1024 + 512, sv, tv);
    if (i == NUM_GAT - 1) {
      agg_kernel<<<N_NODES, 256, 0, stream>>>(sv, tv, hp, off, sdst, xpad, KP);
    } else {
      agg_kernel<<<N_NODES, 256, 0, stream>>>(sv, tv, hp, off, sdst, hb, 512);
      bf16* tmp = ha; ha = hb; hb = tmp;
    }
  }

  // ---- output MLP3 + sigmoid (xpad already holds [h, goal, info])
  gemm_kernel<<<gg, 256, 0, stream>>>(xpad, v1t, hB, KP, vb1, 1);
  gemm_kernel<<<gg, 256, 0, stream>>>(hB, v2t, hp, 512, vb2, 1);
  final_kernel<<<(N_NODES * 64 + 255) / 256, 256, 0, stream>>>(hp, V3, vb3, out);
}

// Round 11
// 677.138 us; speedup vs baseline: 1.2285x; 1.0540x over previous
//
#include <hip/hip_runtime.h>
#include <hip/hip_bf16.h>
#include <stdint.h>

typedef __bf16 bf16;
typedef __bf16 bf16x8 __attribute__((ext_vector_type(8)));
typedef float floatx4 __attribute__((ext_vector_type(4)));

#define N_NODES 20000
#define MP 20096          // 157*128, padded M
#define HDIM 512
#define KP 1088           // 1029 padded to multiple of 64 (17 BK-iters, 136 chunks)
#define KCH 136
#define FEATD 1029
#define NUM_GAT 5
#define ROWT (MP / 128)   // 157 row tiles

// ---- async global->LDS, 16B per lane; LDS base must be wave-uniform ----------
typedef __attribute__((address_space(1))) void as1_void;
typedef __attribute__((address_space(3))) void as3_void;
__device__ __forceinline__ void gl_lds16(const void* g, void* l) {
  __builtin_amdgcn_global_load_lds(
      (as1_void*)(uintptr_t)g, (as3_void*)(uintptr_t)l, 16, 0, 0);
}

// ------- pack x = concat(feat, goal, info) fp32 -> bf16 [MP][KP]; zero cur -----
__global__ void pack_kernel(const float* __restrict__ a, const float* __restrict__ goal,
                            const float* __restrict__ info, bf16* __restrict__ xp,
                            int* __restrict__ cur) {
  int idx = blockIdx.x * 256 + threadIdx.x;
  if (idx <= N_NODES) cur[idx] = 0;          // fused zero_kernel (proven r5-r10)
  if (idx >= MP * KCH) return;
  int row = idx / KCH, c = idx % KCH;
  bf16x8 o = {};
  if (row < N_NODES) {
    if (c < 64) {
      const float* p = a + (size_t)row * 512 + c * 8;
      #pragma unroll
      for (int j = 0; j < 8; ++j) o[j] = (bf16)p[j];
    } else if (c < 128) {
      const float* p = goal + (size_t)row * 512 + (c - 64) * 8;
      #pragma unroll
      for (int j = 0; j < 8; ++j) o[j] = (bf16)p[j];
    } else if (c == 128) {
      #pragma unroll
      for (int j = 0; j < 5; ++j) o[j] = (bf16)info[(size_t)row * 5 + j];
    }
  }
  *(bf16x8*)(xp + (size_t)row * KP + c * 8) = o;
}

// ------- LDS-tiled transpose: 8 square 512x512 fp32 -> bf16 [512][512] ---------
struct Ptr8 { const float* p[8]; };
__global__ __launch_bounds__(256) void transpose_sq_kernel(Ptr8 srcs, bf16* __restrict__ dst) {
  __shared__ float tile[64][65];
  int b = blockIdx.x;                  // 8 mats x 64 tiles
  int z = b >> 6, rem = b & 63;
  int kt = rem >> 3, nt = rem & 7;
  int k0 = kt * 64, n0 = nt * 64;
  const float* src = srcs.p[z];
  #pragma unroll
  for (int i = 0; i < 16; ++i) {
    int id = threadIdx.x + i * 256;
    int kk = id >> 6, nn = id & 63;
    tile[kk][nn] = src[(size_t)(k0 + kk) * 512 + n0 + nn];
  }
  __syncthreads();
  #pragma unroll
  for (int i = 0; i < 16; ++i) {
    int id = threadIdx.x + i * 256;
    int nn = id >> 6, kk = id & 63;
    dst[(size_t)z * 512 * 512 + (size_t)(n0 + nn) * 512 + k0 + kk] = (bf16)tile[kk][nn];
  }
}

// ------- LDS-tiled transpose: 2 wide 1029x512 fp32 -> bf16 [512][1088], pad ----
struct Ptr2 { const float* p[2]; };
__global__ __launch_bounds__(256) void transpose_wide_kernel(Ptr2 srcs, bf16* __restrict__ dst) {
  __shared__ float tile[64][65];
  int b = blockIdx.x;                  // 2 mats x (17 ktiles x 8 ntiles)
  int z = b / 136, rem = b % 136;
  int kt = rem >> 3, nt = rem & 7;
  int k0 = kt * 64, n0 = nt * 64;
  const float* src = srcs.p[z];
  #pragma unroll
  for (int i = 0; i < 16; ++i) {
    int id = threadIdx.x + i * 256;
    int kk = id >> 6, nn = id & 63;
    int k = k0 + kk;
    tile[kk][nn] = (k < FEATD) ? src[(size_t)k * 512 + n0 + nn] : 0.f;
  }
  __syncthreads();
  #pragma unroll
  for (int i = 0; i < 16; ++i) {
    int id = threadIdx.x + i * 256;
    int nn = id >> 6, kk = id & 63;
    dst[(size_t)z * 512 * KP + (size_t)(n0 + nn) * KP + k0 + kk] = (bf16)tile[kk][nn];
  }
}

// ---------------- CSR build ----------------------------------------------------
__global__ void hist_kernel(const int* __restrict__ src, int* __restrict__ cnt, int E) {
  int e = blockIdx.x * 256 + threadIdx.x;
  if (e < E) atomicAdd(&cnt[src[e]], 1);
}
__global__ __launch_bounds__(1024) void scan_kernel(int* __restrict__ cnt,
                                                    int* __restrict__ off, int n) {
  __shared__ int wsum[16];
  __shared__ int carry_s;
  int tid = threadIdx.x, lane = tid & 63, w = tid >> 6;
  if (tid == 0) carry_s = 0;
  __syncthreads();
  for (int base = 0; base < n; base += 1024) {
    int i = base + tid;
    int v = (i < n) ? cnt[i] : 0;
    int x = v;  // inclusive wave scan
    #pragma unroll
    for (int o = 1; o < 64; o <<= 1) {
      int y = __shfl_up(x, o);
      if (lane >= o) x += y;
    }
    if (lane == 63) wsum[w] = x;
    __syncthreads();
    int wpre = 0;
    for (int j = 0; j < w; ++j) wpre += wsum[j];
    int incl = x + wpre;
    int c = carry_s;
    if (i < n) { int ex = c + incl - v; off[i] = ex; cnt[i] = ex; }
    __syncthreads();
    if (tid == 1023) carry_s = c + incl;
    __syncthreads();
  }
  if (tid == 0) off[n] = carry_s;
}
__global__ void scatter_kernel(const int* __restrict__ src, const int* __restrict__ dstv,
                               int* __restrict__ cur, int* __restrict__ sdst, int E) {
  int e = blockIdx.x * 256 + threadIdx.x;
  if (e < E) {
    int p = atomicAdd(&cur[src[e]], 1);
    sdst[p] = dstv[e];
  }
}

// ------- bf16 MFMA GEMM (v7, empirical optimum): C[M][512] = A @ BT^T ----------
// 128x64 tile, BK=64, LDS 48KB -> 3 blocks/CU, double-buffered
// global_load_lds with counted vmcnt(6) + raw s_barrier, XOR-swizzled chunks
// (conflict-free ds_read_b128). Tile-space mapped across the session:
//   128x128/BK=64 (2 blk/CU, 2.45-round tail)      -> 723us total (r3)
//   128x64 /BK=64 (this)                           -> 684us total (r4)
//   B-from-L2, no sB (latency in compute phase)    -> 832us total (r6)
//   128x128/BK=32 (4 blk/CU but 2x barrier rate)   -> 714us total (r10)
// Lessons: MFMA operands must come from LDS; barrier frequency matters as
// much as the ds_read:MFMA ratio. XCD trick: the 8 col tiles of one A
// row-strip sit 8 apart in dispatch order -> same XCD -> A fetched ~once.
__global__ __launch_bounds__(256) void gemm_kernel(
    const bf16* __restrict__ A, const bf16* __restrict__ BT, bf16* __restrict__ C,
    int K, const float* __restrict__ bias, int relu) {
  __shared__ __align__(16) bf16 sA[2][128 * 64];
  __shared__ __align__(16) bf16 sB[2][64 * 64];
  const int flat = blockIdx.x;
  const int rowT = ((flat >> 6) << 3) | (flat & 7);
  const int colT = (flat >> 3) & 7;
  if (rowT >= ROWT) return;
  const int tid = threadIdx.x;
  const int lane = tid & 63, wid = tid >> 6;
  const int wr = (wid >> 1) * 64;      // wave row offset: 0 or 64
  const int wc = (wid & 1) * 32;       // wave col offset: 0 or 32
  const int rowBase = rowT * 128;
  const int colBase = colT * 64;
  const int lrow = lane & 15, lquad = lane >> 4;
  const int xk = lrow & 7;  // read-side XOR key

  floatx4 acc[4][2] = {};
  const int nk = K >> 6;

  auto stage = [&](int buf, int k0) {
    #pragma unroll
    for (int i = 0; i < 4; ++i) {
      int idx = tid + i * 256;            // 0..1023: A tile 128 rows x 8 chunks
      int rr = idx >> 3, cc = idx & 7;
      int gch = cc ^ (rr & 7);            // swizzled global chunk
      gl_lds16(A + (size_t)(rowBase + rr) * K + k0 + gch * 8,
               &sA[buf][(size_t)(wid * 64 + i * 256) * 8]);
    }
    #pragma unroll
    for (int i = 0; i < 2; ++i) {
      int idx = tid + i * 256;            // 0..511: B tile 64 rows x 8 chunks
      int rr = idx >> 3, cc = idx & 7;
      int gch = cc ^ (rr & 7);
      gl_lds16(BT + (size_t)(colBase + rr) * K + k0 + gch * 8,
               &sB[buf][(size_t)(wid * 64 + i * 256) * 8]);
    }
  };

  stage(0, 0);
  for (int kt = 0; kt < nk; ++kt) {
    const int cur = kt & 1;
    if (kt + 1 < nk) {
      stage(cur ^ 1, (kt + 1) << 6);
      // vmcnt(6): wait for current buffer's 6 loads; prefetch stays in flight.
      __builtin_amdgcn_s_waitcnt(0xF76);
    } else {
      __builtin_amdgcn_s_waitcnt(0xF70);  // vmcnt(0)
    }
    __builtin_amdgcn_s_barrier();
    #pragma unroll
    for (int kk = 0; kk < 2; ++kk) {
      bf16x8 af[4], bfr[2];
      #pragma unroll
      for (int mi = 0; mi < 4; ++mi)
        af[mi] = *(const bf16x8*)&sA[cur][(wr + mi * 16 + lrow) * 64 +
                                         (((kk * 4 + lquad) ^ xk) * 8)];
      #pragma unroll
      for (int ni = 0; ni < 2; ++ni)
        bfr[ni] = *(const bf16x8*)&sB[cur][(wc + ni * 16 + lrow) * 64 +
                                          (((kk * 4 + lquad) ^ xk) * 8)];
      #pragma unroll
      for (int mi = 0; mi < 4; ++mi)
        #pragma unroll
        for (int ni = 0; ni < 2; ++ni)
          acc[mi][ni] = __builtin_amdgcn_mfma_f32_16x16x32_bf16(af[mi], bfr[ni], acc[mi][ni], 0, 0, 0);
    }
    // ds_reads complete (consumed by MFMA) before this barrier; next stage()
    // may then safely overwrite the buffer other waves just read.
    __builtin_amdgcn_s_barrier();
  }

  #pragma unroll
  for (int ni = 0; ni < 2; ++ni) {
    int col = colBase + wc + ni * 16 + lrow;
    float bv = bias ? bias[col] : 0.f;
    #pragma unroll
    for (int mi = 0; mi < 4; ++mi) {
      #pragma unroll
      for (int r = 0; r < 4; ++r) {
        int row = rowBase + wr + mi * 16 + lquad * 4 + r;
        float v = acc[mi][ni][r] + bv;
        if (relu) v = fmaxf(v, 0.f);
        C[(size_t)row * HDIM + col] = (bf16)v;
      }
    }
  }
}

// ---------------- s = h'@a1, t = h'@a2 (wave per node; a fp32) -----------------
__global__ void st_kernel(const bf16* __restrict__ hp, const float* __restrict__ a1,
                          const float* __restrict__ a2, float* __restrict__ s,
                          float* __restrict__ t) {
  int gid = blockIdx.x * 256 + threadIdx.x;
  int node = gid >> 6, lane = gid & 63;
  if (node >= N_NODES) return;
  bf16x8 hv = *(const bf16x8*)(hp + (size_t)node * 512 + lane * 8);
  float ps = 0.f, pt = 0.f;
  #pragma unroll
  for (int q = 0; q < 8; ++q) {
    float h = (float)hv[q];
    ps += h * a1[lane * 8 + q];
    pt += h * a2[lane * 8 + q];
  }
  #pragma unroll
  for (int o = 32; o > 0; o >>= 1) {
    ps += __shfl_xor(ps, o);
    pt += __shfl_xor(pt, o);
  }
  if (lane == 0) { s[node] = ps; t[node] = pt; }
}

// ------- GAT aggregation (v7, proven floor): 4 waves/node + swizzled combine ---
// agg is latency/concurrency-bound at its structural floor (~46us across 4
// structural variants; FETCH ~144MB = each XCD streams each needed h-row
// ~once for a random graph). den is lane-uniform: no cross-lane reduce.
__global__ __launch_bounds__(256) void agg_kernel(
    const float* __restrict__ s, const float* __restrict__ t,
    const bf16* __restrict__ hp, const int* __restrict__ off,
    const int* __restrict__ sdst, bf16* __restrict__ hout, int ostride) {
  __shared__ __align__(16) float sacc[4][512];
  __shared__ float sden[4];
  const int wid = threadIdx.x >> 6, lane = threadIdx.x & 63;
  const int node = blockIdx.x;
  const int beg = off[node], end = off[node + 1];
  const int cnt = end - beg;
  const int q = (cnt + 3) >> 2;        // per-wave contiguous chunk
  int jb = beg + wid * q;
  int je = jb + q;
  if (jb > end) jb = end;
  if (je > end) je = end;
  const float si = s[node];
  const int lane8 = lane * 8;

  float acc[8] = {0.f, 0.f, 0.f, 0.f, 0.f, 0.f, 0.f, 0.f};
  float den = 0.f;
  int j = jb;
  for (; j + 4 <= je; j += 4) {
    int d0 = sdst[j], d1 = sdst[j + 1], d2 = sdst[j + 2], d3 = sdst[j + 3];
    float t0 = t[d0], t1 = t[d1], t2 = t[d2], t3 = t[d3];
    bf16x8 v0 = *(const bf16x8*)(hp + (size_t)d0 * 512 + lane8);
    bf16x8 v1 = *(const bf16x8*)(hp + (size_t)d1 * 512 + lane8);
    bf16x8 v2 = *(const bf16x8*)(hp + (size_t)d2 * 512 + lane8);
    bf16x8 v3 = *(const bf16x8*)(hp + (size_t)d3 * 512 + lane8);
    float s0 = si + t0, s1 = si + t1, s2 = si + t2, s3 = si + t3;
    float l0 = s0 > 0.f ? s0 : 0.2f * s0;
    float l1 = s1 > 0.f ? s1 : 0.2f * s1;
    float l2 = s2 > 0.f ? s2 : 0.2f * s2;
    float l3 = s3 > 0.f ? s3 : 0.2f * s3;
    float e0 = __expf(-l0), e1 = __expf(-l1), e2 = __expf(-l2), e3 = __expf(-l3);
    den += (e0 + e1) + (e2 + e3);
    #pragma unroll
    for (int qq = 0; qq < 8; ++qq)
      acc[qq] += e0 * (float)v0[qq] + e1 * (float)v1[qq] +
                 e2 * (float)v2[qq] + e3 * (float)v3[qq];
  }
  for (; j < je; ++j) {
    int d = sdst[j];
    float sc = si + t[d];
    float lr = sc > 0.f ? sc : 0.2f * sc;
    float e = __expf(-lr);
    den += e;
    bf16x8 v = *(const bf16x8*)(hp + (size_t)d * 512 + lane8);
    #pragma unroll
    for (int qq = 0; qq < 8; ++qq) acc[qq] += e * (float)v[qq];
  }

  if (lane == 0) sden[wid] = den;   // den identical across lanes
  // swizzled 16B-chunk store: chunk f = lane*2+h at p = f ^ (lane&7);
  // p&7 covers all 8 bank groups across any 8 consecutive lanes.
  #pragma unroll
  for (int h = 0; h < 2; ++h) {
    int p = (lane * 2 + h) ^ (lane & 7);
    floatx4 val = {acc[h * 4 + 0], acc[h * 4 + 1], acc[h * 4 + 2], acc[h * 4 + 3]};
    *(floatx4*)&sacc[wid][p * 4] = val;
  }
  __syncthreads();
  if (wid == 0) {
    float inv = 1.f / (sden[0] + sden[1] + sden[2] + sden[3] + 1e-10f);
    bf16x8 o;
    #pragma unroll
    for (int h = 0; h < 2; ++h) {
      int p = (lane * 2 + h) ^ (lane & 7);
      floatx4 sum = *(const floatx4*)&sacc[0][p * 4];
      #pragma unroll
      for (int w = 1; w < 4; ++w) {
        floatx4 v = *(const floatx4*)&sacc[w][p * 4];
        sum[0] += v[0]; sum[1] += v[1]; sum[2] += v[2]; sum[3] += v[3];
      }
      #pragma unroll
      for (int x = 0; x < 4; ++x)
        o[h * 4 + x] = (bf16)fmaxf(sum[x] * inv, 0.f);   // relu
    }
    *(bf16x8*)(hout + (size_t)node * ostride + lane8) = o;
  }
}

// -------- final: out = sigmoid(t2 @ V3 + vb3), V3/vb3 fp32, out fp32 -----------
__global__ void final_kernel(const bf16* __restrict__ t2, const float* __restrict__ V3,
                             const float* __restrict__ vb3, float* __restrict__ out) {
  int gid = blockIdx.x * 256 + threadIdx.x;
  int node = gid >> 6, lane = gid & 63;
  if (node >= N_NODES) return;
  bf16x8 hv = *(const bf16x8*)(t2 + (size_t)node * 512 + lane * 8);
  float p = 0.f;
  #pragma unroll
  for (int q = 0; q < 8; ++q) p += (float)hv[q] * V3[lane * 8 + q];
  #pragma unroll
  for (int o = 32; o > 0; o >>= 1) p += __shfl_xor(p, o);
  if (lane == 0) {
    float z = p + vb3[0];
    out[node] = 1.f / (1.f + __expf(-z));
  }
}

// ------------------------------------------------------------------------------
extern "C" void kernel_launch(void* const* d_in, const int* in_sizes, int n_in,
                              void* d_out, int out_size, void* d_ws, size_t ws_size,
                              hipStream_t stream) {
  const float* feat = (const float*)d_in[0];
  const float* goal = (const float*)d_in[1];
  const float* info = (const float*)d_in[2];
  const int* esrc   = (const int*)d_in[3];
  const int* edst   = (const int*)d_in[4];
  const float* W1  = (const float*)d_in[5];
  const float* b1  = (const float*)d_in[6];
  const float* W2  = (const float*)d_in[7];
  const float* b2  = (const float*)d_in[8];
  const float* W3  = (const float*)d_in[9];
  const float* b3  = (const float*)d_in[10];
  const float* V1  = (const float*)d_in[11];
  const float* vb1 = (const float*)d_in[12];
  const float* V2  = (const float*)d_in[13];
  const float* vb2 = (const float*)d_in[14];
  const float* V3  = (const float*)d_in[15];
  const float* vb3 = (const float*)d_in[16];
  const float* gatW = (const float*)d_in[17];
  const float* gatA = (const float*)d_in[18];
  float* out = (float*)d_out;
  const int E = in_sizes[3];
  const size_t SQ = 512 * 512;

  // ---- carve workspace
  char* w = (char*)d_ws;
  auto alloc = [&](size_t bytes) {
    char* p = w;
    w += (bytes + 255) & ~(size_t)255;
    return p;
  };
  bf16* xpad = (bf16*)alloc((size_t)MP * KP * 2);
  bf16* wkt  = (bf16*)alloc((size_t)2 * 512 * KP * 2);   // [0]=W1T, [1]=V1T
  bf16* wsq  = (bf16*)alloc((size_t)8 * SQ * 2);         // W2,W3,V2,gatW[0..4]
  bf16* hA   = (bf16*)alloc((size_t)MP * 512 * 2);
  bf16* hB   = (bf16*)alloc((size_t)MP * 512 * 2);
  bf16* hp   = (bf16*)alloc((size_t)MP * 512 * 2);
  float* sv  = (float*)alloc((size_t)N_NODES * 4);
  float* tv  = (float*)alloc((size_t)N_NODES * 4);
  int* off   = (int*)alloc((size_t)(N_NODES + 1) * 4);
  int* cur   = (int*)alloc((size_t)(N_NODES + 1) * 4);
  int* sdst  = (int*)alloc((size_t)E * 4);

  bf16* w1t = wkt;
  bf16* v1t = wkt + (size_t)512 * KP;
  bf16* w2t = wsq;
  bf16* w3t = wsq + SQ;
  bf16* v2t = wsq + 2 * SQ;
  bf16* gwt = wsq + 3 * SQ;

  const int eb = (E + 255) / 256;

  // ---- pack x (+ zero cur), transpose+convert weights (LDS-tiled)
  pack_kernel<<<(MP * KCH + 255) / 256, 256, 0, stream>>>(feat, goal, info, xpad, cur);
  Ptr2 wide; wide.p[0] = W1; wide.p[1] = V1;
  transpose_wide_kernel<<<2 * 136, 256, 0, stream>>>(wide, wkt);
  Ptr8 sq;
  sq.p[0] = W2; sq.p[1] = W3; sq.p[2] = V2;
  for (int i = 0; i < NUM_GAT; ++i) sq.p[3 + i] = gatW + (size_t)i * SQ;
  transpose_sq_kernel<<<8 * 64, 256, 0, stream>>>(sq, wsq);

  // ---- CSR build (sorted-by-src gather lists)
  hist_kernel<<<eb, 256, 0, stream>>>(esrc, cur, E);
  scan_kernel<<<1, 1024, 0, stream>>>(cur, off, N_NODES);
  scatter_kernel<<<eb, 256, 0, stream>>>(esrc, edst, cur, sdst, E);

  const int gg = 1280;  // 160 row tiles x 8 col tiles, XCD-swizzled flat grid
  // ---- input MLP3
  gemm_kernel<<<gg, 256, 0, stream>>>(xpad, w1t, hA, KP, b1, 1);
  gemm_kernel<<<gg, 256, 0, stream>>>(hA, w2t, hB, 512, b2, 1);
  gemm_kernel<<<gg, 256, 0, stream>>>(hB, w3t, hA, 512, b3, 0);

  // ---- GAT layers (layer 4 writes straight into xpad cols 0..511)
  bf16* ha = hA;
  bf16* hb = hB;
  for (int i = 0; i < NUM_GAT; ++i) {
    gemm_kernel<<<gg, 256, 0, stream>>>(ha, gwt + (size_t)i * SQ, hp, 512,
                                        (const float*)nullptr, 0);
    st_kernel<<<(N_NODES * 64 + 255) / 256, 256, 0, stream>>>(
        hp, gatA + (size_t)i * 1024, gatA + (size_t)i * 1024 + 512, sv, tv);
    if (i == NUM_GAT - 1) {
      agg_kernel<<<N_NODES, 256, 0, stream>>>(sv, tv, hp, off, sdst, xpad, KP);
    } else {
      agg_kernel<<<N_NODES, 256, 0, stream>>>(sv, tv, hp, off, sdst, hb, 512);
      bf16* tmp = ha; ha = hb; hb = tmp;
    }
  }

  // ---- output MLP3 + sigmoid (xpad already holds [h, goal, info])
  gemm_kernel<<<gg, 256, 0, stream>>>(xpad, v1t, hB, KP, vb1, 1);
  gemm_kernel<<<gg, 256, 0, stream>>>(hB, v2t, hp, 512, vb2, 1);
  final_kernel<<<(N_NODES * 64 + 255) / 256, 256, 0, stream>>>(hp, V3, vb3, out);
}